// Round 10
// baseline (583.244 us; speedup 1.0000x reference)
//
#include <hip/hip_runtime.h>
#include <math.h>

#define HN 512   // hidden states
#define HM 4096  // emission symbols
#define HB 64    // batch
#define HT 512   // max seq len

// ---- 4-bit dot path (encoding must match between prep + fwd) ----
#if __has_builtin(__builtin_amdgcn_udot8)
  #define ENC_BIASED 0
  __device__ __forceinline__ int dot8q(unsigned int a, unsigned int b, int c){
    return (int)__builtin_amdgcn_udot8(a, b, (unsigned int)c, false);
  }
#elif __has_builtin(__builtin_amdgcn_sdot8)
  #define ENC_BIASED 1
  __device__ __forceinline__ int dot8q(unsigned int a, unsigned int b, int c){
    return __builtin_amdgcn_sdot8((int)a, (int)b, c, false);
  }
#else
  #define ENC_BIASED 0
  __device__ __forceinline__ int dot4u8f(unsigned int a, unsigned int b, int c){
#if __has_builtin(__builtin_amdgcn_sdot4)
    return __builtin_amdgcn_sdot4((int)a, (int)b, c, false);   // vals<=15, sign-safe
#else
    c += (int)(a & 0xffu)       * (int)(b & 0xffu);
    c += (int)((a>>8) & 0xffu)  * (int)((b>>8) & 0xffu);
    c += (int)((a>>16) & 0xffu) * (int)((b>>16) & 0xffu);
    c += (int)(a>>24)           * (int)(b>>24);
    return c;
#endif
  }
  __device__ __forceinline__ int dot8q(unsigned int a, unsigned int b, int c){
    unsigned int al = a & 0x0F0F0F0Fu, ah = (a>>4) & 0x0F0F0F0Fu;
    unsigned int bl = b & 0x0F0F0F0Fu, bh = (b>>4) & 0x0F0F0F0Fu;
    c = dot4u8f(al, bl, c);
    return dot4u8f(ah, bh, c);
  }
#endif

__device__ __forceinline__ float rcpf(float x){
#if __has_builtin(__builtin_amdgcn_rcpf)
  return __builtin_amdgcn_rcpf(x);
#else
  return 1.0f / x;
#endif
}

__device__ __forceinline__ float wsum(float v){
  #pragma unroll
  for(int o=32;o>0;o>>=1) v += __shfl_xor(v,o,64);
  return v;
}
__device__ __forceinline__ float wmax(float v){
  #pragma unroll
  for(int o=32;o>0;o>>=1) v = fmaxf(v,__shfl_xor(v,o,64));
  return v;
}

// ---- DPP wave64 reductions (VALU-latency, not DS-pipe) ----
#if __has_builtin(__builtin_amdgcn_update_dpp) && __has_builtin(__builtin_amdgcn_readlane)
#define HAVE_DPP 1
#define DPPF(v, ctrl, rmask) \
  __int_as_float(__builtin_amdgcn_update_dpp(0, __float_as_int(v), (ctrl), (rmask), 0xf, true))
__device__ __forceinline__ float wsum_nn(float v){   // sum of nonneg, result uniform
  v += DPPF(v, 0x111, 0xf);   // row_shr:1
  v += DPPF(v, 0x112, 0xf);   // row_shr:2
  v += DPPF(v, 0x114, 0xf);   // row_shr:4
  v += DPPF(v, 0x118, 0xf);   // row_shr:8
  v += DPPF(v, 0x142, 0xa);   // row_bcast:15 -> rows 1,3
  v += DPPF(v, 0x143, 0xc);   // row_bcast:31 -> rows 2,3
  return __int_as_float(__builtin_amdgcn_readlane(__float_as_int(v), 63));
}
__device__ __forceinline__ float wmax_nn(float v){   // max of nonneg, result uniform
  v = fmaxf(v, DPPF(v, 0x111, 0xf));
  v = fmaxf(v, DPPF(v, 0x112, 0xf));
  v = fmaxf(v, DPPF(v, 0x114, 0xf));
  v = fmaxf(v, DPPF(v, 0x118, 0xf));
  v = fmaxf(v, DPPF(v, 0x142, 0xa));
  v = fmaxf(v, DPPF(v, 0x143, 0xc));
  return __int_as_float(__builtin_amdgcn_readlane(__float_as_int(v), 63));
}
__device__ __forceinline__ int xor1_i(int v){        // lane^1 exchange, quad_perm [1,0,3,2]
  return __builtin_amdgcn_update_dpp(0, v, 0x0B1, 0xf, 0xf, true);
}
#else
#define HAVE_DPP 0
__device__ __forceinline__ float wsum_nn(float v){ return wsum(v); }
__device__ __forceinline__ float wmax_nn(float v){ return wmax(v); }
__device__ __forceinline__ int xor1_i(int v){ return __shfl_xor(v, 1, 64); }
#endif

__device__ __forceinline__ float blockSum512(float v, float* red, float* bc){
  v = wsum(v);
  if((threadIdx.x & 63)==0) red[threadIdx.x>>6] = v;
  __syncthreads();
  if(threadIdx.x < 64){
    float s = (threadIdx.x<8)? red[threadIdx.x] : 0.0f;
    #pragma unroll
    for(int o=4;o>0;o>>=1) s += __shfl_xor(s,o,64);
    if(threadIdx.x==0) *bc = s;
  }
  __syncthreads();
  return *bc;
}
__device__ __forceinline__ float blockMax512(float v, float* red, float* bc){
  v = wmax(v);
  if((threadIdx.x & 63)==0) red[threadIdx.x>>6] = v;
  __syncthreads();
  if(threadIdx.x < 64){
    float s = (threadIdx.x<8)? red[threadIdx.x] : -INFINITY;
    #pragma unroll
    for(int o=4;o>0;o>>=1) s = fmaxf(s, __shfl_xor(s,o,64));
    if(threadIdx.x==0) *bc = s;
  }
  __syncthreads();
  return *bc;
}

__device__ __forceinline__ unsigned short f2bf(float f){
  unsigned int u = __float_as_uint(f);
  unsigned int r = (u + 0x7fffu + ((u>>16)&1u)) >> 16;  // RNE
  return (unsigned short)r;
}
__device__ __forceinline__ float bf2f(unsigned int w){ return __uint_as_float(w<<16); }

// ---------------- prep kernels ----------------

__global__ __launch_bounds__(512) void k_em_lse(const float* __restrict__ em, float* __restrict__ em_lse){
  __shared__ float red[8]; __shared__ float bc;
  int r = blockIdx.x;
  const float* row = em + (size_t)r*HM;
  float mx = -INFINITY;
  for(int i=threadIdx.x;i<HM;i+=512) mx = fmaxf(mx, row[i]);
  mx = blockMax512(mx, red, &bc);
  float s = 0.f;
  for(int i=threadIdx.x;i<HM;i+=512) s += expf(row[i]-mx);
  s = blockSum512(s, red, &bc);
  if(threadIdx.x==0) em_lse[r] = mx + logf(s);
}

// emT[m][j] = bf16( exp(log_em[j][m]) ), LDS-tiled transpose
__global__ __launch_bounds__(256) void k_em_tab(const float* __restrict__ em, const float* __restrict__ em_lse,
                                                unsigned short* __restrict__ emT){
  __shared__ unsigned short tile[64][66];
  __shared__ float lsl[64];
  int m0 = blockIdx.x*64, j0 = blockIdx.y*64;
  int tx = threadIdx.x & 63, ty = threadIdx.x >> 6;
  if(threadIdx.x < 64) lsl[threadIdx.x] = em_lse[j0 + threadIdx.x];
  __syncthreads();
  #pragma unroll
  for(int r=0;r<16;r++){
    int jl = ty*16 + r;
    float v = em[(size_t)(j0+jl)*HM + m0 + tx];
    tile[jl][tx] = f2bf(expf(v - lsl[jl]));
  }
  __syncthreads();
  #pragma unroll
  for(int r=0;r<16;r++){
    int ml = ty*16 + r;
    emT[(size_t)(m0+ml)*HN + j0 + tx] = tile[tx][ml];
  }
}

// column stats of transition col-softmax; block 0 also handles the prior
__global__ __launch_bounds__(512) void k_trcol(const float* __restrict__ tr,
                                               float* __restrict__ cmax, float* __restrict__ csum,
                                               const float* __restrict__ pri,
                                               float* __restrict__ P, float* __restrict__ pric){
  __shared__ float red[8]; __shared__ float bc;
  int k = blockIdx.x, j = threadIdx.x;
  float v = tr[(size_t)j*HN + k];
  float mx = blockMax512(v, red, &bc);
  float s  = blockSum512(expf(v-mx), red, &bc);
  if(j==0){ cmax[k] = mx; csum[k] = s; }
  if(blockIdx.x == 0){
    float pv = pri[j];
    float pmx = blockMax512(pv, red, &bc);
    float pw = expf(pv-pmx);
    float ps = blockSum512(pw, red, &bc);
    P[j] = pw;
    if(j==0) *pric = -logf(ps);
  }
}

// row pass: Tr[j,k] -> u4 q = round(Tr*15/rowmax). Byte at j*256 + (k>>5)*16 +
// ((k&31)>>1): lo = even k, hi = k+1 (matches alpha packing).
// rscale[j]=rm/15; rbar[j]=rowsum residual; tsumq[j][w] = per-64k-slice q sum.
__global__ __launch_bounds__(512) void k_trrow(const float* __restrict__ tr,
                                               const float* __restrict__ cmax, const float* __restrict__ csum,
                                               unsigned char* __restrict__ TQ4,
                                               float* __restrict__ rscale, float* __restrict__ rbar,
                                               unsigned short* __restrict__ tsumq){
  __shared__ float red[8]; __shared__ float bc;
  int j = blockIdx.x, k = threadIdx.x;
  float v = expf(tr[(size_t)j*HN + k] - cmax[k]) / csum[k];
  float rm = blockMax512(v, red, &bc);
  int q = __float2int_rn(v * (15.0f/rm));          // 0..15
  float rs = blockSum512(v, red, &bc);             // true row sum
  float qs = blockSum512((float)q, red, &bc);      // total q sum
  float wq = wsum((float)q);                       // per-wave(64k) q sum
  int qn = __shfl_down(q, 1, 64);
  if((k & 1)==0){
#if ENC_BIASED
    unsigned char by = (unsigned char)(((q-8)&0xF) | (((qn-8)&0xF)<<4));
#else
    unsigned char by = (unsigned char)((q&0xF) | ((qn&0xF)<<4));
#endif
    TQ4[(size_t)j*256 + ((k>>5)<<4) + ((k&31)>>1)] = by;
  }
  if((k&63)==0) tsumq[j*8 + (k>>6)] = (unsigned short)(int)wq;
  if(k==0){
    rscale[j] = rm * (1.0f/15.0f);
    rbar[j]   = rs - (rm * (1.0f/15.0f)) * qs;
  }
}

// ---------------- forward recurrence ----------------
// ROUND 10 (see analysis above): R8's 5/11 LDS/scratch split +
// amdgpu_waves_per_eu(2,2) (proven VGPR-budget unlock, R3/R6/R7) + explicit
// load-phase/dot-phase with short-lived named temps so both pipes' loads are
// in flight together. LDS-chunk dots run first so the scratch stream drains
// under them. Predict step ~1450-1600 cyc -> k_fwd ~310-350us.
__global__ __launch_bounds__(512) __attribute__((amdgpu_waves_per_eu(2, 2)))
void k_fwd(const int* __restrict__ x, const int* __restrict__ Tl,
           const unsigned short* __restrict__ emTu,
           const float* __restrict__ P, const float* __restrict__ pric,
           const float* __restrict__ rscaleG, const float* __restrict__ rbarG,
           const unsigned short* __restrict__ tsumqG,
           const uint4* __restrict__ TQd4,
           float* __restrict__ out){
  extern __shared__ char smem[];
  uint4*         tq4   = (uint4*)smem;                         // 128 KiB swizzled Tr
  char*          sm2   = smem + 131072;
  uint4*         apl4  = (uint4*)sm2;                          // [2][16] uint4 = 512 B
  unsigned char* aplB  = (unsigned char*)sm2;
  float*         sigS  = (float*)(sm2 + 512);                  // [2][8]
  float*         sumS  = (float*)(sm2 + 576);                  // [2][8]
  float*         aqS   = (float*)(sm2 + 640);                  // [2][8]
  float*         rawS  = (float*)(sm2 + 704);                  // [8]
  int*           xls   = (int*)(sm2 + 768);                    // 2048
  float*         rscL  = (float*)(sm2 + 2816);                 // 2048
  float*         rbarL = (float*)(sm2 + 4864);                 // 2048
  unsigned short* tsumL= (unsigned short*)(sm2 + 6912);        // 8192

  const int t = threadIdx.x, b = blockIdx.x, w = t>>6, L = t&63;
  const int j = t;

  // ---- stage (1): full Tr (128 KB) -> LDS, chunk-XOR swizzled ----
  #pragma unroll
  for(int p=0;p<16;p++){
    int i = t + p*512;
    uint4 v = TQd4[i];
    int r = i>>4, c = i&15;
    tq4[(r<<4) + (c ^ (r&15))] = v;
  }
  // ---- stage (2): own row chunks 5..15 -> scratch array ----
  unsigned int trq[44];
  #pragma unroll
  for(int q=5;q<16;q++) ((uint4*)trq)[q-5] = TQd4[j*16 + q];
  #pragma unroll
  for(int r=0;r<44;r++) asm volatile("" : "+v"(trq[r]));

  xls[t]   = x[b*HT + t];
  rscL[t]  = rscaleG[t];
  rbarL[t] = rbarG[t];
  for(int d=t; d<2048; d+=512) ((unsigned int*)tsumL)[d] = ((const unsigned int*)tsumqG)[d];
  int Tb = Tl[b];
  __syncthreads();

  const int myrow = j<<4, mys = j&15;

  // ---- init (t = 0) ----
  int m = xls[0];
  float e0 = bf2f((unsigned)emTu[(size_t)m*HN + j]);
  float nvr = e0 * P[j];
  {
    float s = wsum_nn(nvr);
    if(L==0) rawS[w] = s;
  }
  __syncthreads();
  float4 q0 = ((float4*)rawS)[0], q1 = ((float4*)rawS)[1];
  float S0 = ((q0.x+q0.y)+(q0.z+q0.w))+((q1.x+q1.y)+(q1.z+q1.w));
  float c_acc = pric[0] + __logf(S0);
  float nvd = nvr * rcpf(S0);
  {
    float Mw = fmaxf(wmax_nn(nvd), 1e-30f);
    float sig = Mw * (1.0f/15.0f);
    int aq = __float2int_rn(nvd * (15.0f * rcpf(Mw)));
    float Sw = wsum_nn(nvd);
#if ENC_BIASED
    float AqSw = wsum_nn((float)aq);
#endif
    int aqn = xor1_i(aq);
    if((j&1)==0){
#if ENC_BIASED
      aplB[256 + (j>>1)] = (unsigned char)(((aq-8)&0xF) | (((aqn-8)&0xF)<<4));
#else
      aplB[256 + (j>>1)] = (unsigned char)((aq&0xF) | ((aqn&0xF)<<4));
#endif
    }
    if(L==0){
      sigS[8+w] = sig; sumS[8+w] = Sw;
#if ENC_BIASED
      aqS[8+w] = AqSw;
#endif
    }
  }
  int mn = xls[(Tb>1)?1:0];
  float eC = bf2f((unsigned)emTu[(size_t)mn*HN + j]);
  const float rsc = rscL[j], rbr = rbarL[j];

  for(int tt=1; tt<Tb; tt++){
    __syncthreads();
    const int rb = (tt & 1), wb = rb ^ 1;
    const uint4* aplR = apl4 + 16*rb;

    // [a-load] all loads into short-lived named temps (both pipes in flight)
    uint4 A0 = aplR[0],  A1 = aplR[1],  A2 = aplR[2],  A3 = aplR[3];
    uint4 A4 = aplR[4],  A5 = aplR[5],  A6 = aplR[6],  A7 = aplR[7];
    uint4 A8 = aplR[8],  A9 = aplR[9],  A10= aplR[10], A11= aplR[11];
    uint4 A12= aplR[12], A13= aplR[13], A14= aplR[14], A15= aplR[15];
    uint4 T0 = tq4[myrow + (0 ^ mys)];
    uint4 T1 = tq4[myrow + (1 ^ mys)];
    uint4 T2 = tq4[myrow + (2 ^ mys)];
    uint4 T3 = tq4[myrow + (3 ^ mys)];
    uint4 T4 = tq4[myrow + (4 ^ mys)];
    uint4 S5 = ((const uint4*)trq)[0],  S6 = ((const uint4*)trq)[1];
    uint4 S7 = ((const uint4*)trq)[2],  S8 = ((const uint4*)trq)[3];
    uint4 S9 = ((const uint4*)trq)[4],  S10= ((const uint4*)trq)[5];
    uint4 S11= ((const uint4*)trq)[6],  S12= ((const uint4*)trq)[7];
    uint4 S13= ((const uint4*)trq)[8],  S14= ((const uint4*)trq)[9];
    uint4 S15= ((const uint4*)trq)[10];

    // [a-dot] LDS chunks first; scratch chunks drain underneath
    int acc[8];
    #pragma unroll
    for(int i=0;i<8;i++) acc[i] = 0;
#define D4(Tv, Av, wi) { \
    acc[wi] = dot8q(Tv.x, Av.x, acc[wi]); \
    acc[wi] = dot8q(Tv.y, Av.y, acc[wi]); \
    acc[wi] = dot8q(Tv.z, Av.z, acc[wi]); \
    acc[wi] = dot8q(Tv.w, Av.w, acc[wi]); }
    D4(T0, A0, 0) D4(T1, A1, 0) D4(T2, A2, 1) D4(T3, A3, 1) D4(T4, A4, 2)
    D4(S5, A5, 2) D4(S6, A6, 3) D4(S7, A7, 3)
    D4(S8, A8, 4) D4(S9, A9, 4) D4(S10, A10, 5) D4(S11, A11, 5)
    D4(S12, A12, 6) D4(S13, A13, 6) D4(S14, A14, 7) D4(S15, A15, 7)
#undef D4

    // [b] previous-step stats (uniform reads)
    float4 g0 = ((float4*)(sumS + 8*rb))[0], g1 = ((float4*)(sumS + 8*rb))[1];
    float Sp = ((g0.x+g0.y)+(g0.z+g0.w))+((g1.x+g1.y)+(g1.z+g1.w));
    if(tt > 1) c_acc += __logf(Sp);
    float d_inv = rcpf(Sp);
    float abar  = Sp * (1.0f/512.0f);
    float4 s0 = ((float4*)(sigS + 8*rb))[0], s1 = ((float4*)(sigS + 8*rb))[1];
    float sg[8] = {s0.x,s0.y,s0.z,s0.w,s1.x,s1.y,s1.z,s1.w};

    // [c] combine with per-slice alpha scales (+ sdot bias correction)
    float Af = 0.f;
#if ENC_BIASED
    {
      float4 a0 = ((float4*)(aqS + 8*rb))[0], a1 = ((float4*)(aqS + 8*rb))[1];
      float av[8] = {a0.x,a0.y,a0.z,a0.w,a1.x,a1.y,a1.z,a1.w};
      uint4 tq = ((const uint4*)tsumL)[j];
      int ts[8] = {(int)(tq.x&0xffff),(int)(tq.x>>16),(int)(tq.y&0xffff),(int)(tq.y>>16),
                   (int)(tq.z&0xffff),(int)(tq.z>>16),(int)(tq.w&0xffff),(int)(tq.w>>16)};
      #pragma unroll
      for(int i=0;i<8;i++)
        Af += sg[i] * (float)(acc[i] + 8*(ts[i] + (int)av[i]) - 4096);
    }
#else
    #pragma unroll
    for(int i=0;i<8;i++) Af += sg[i] * (float)acc[i];
#endif
    float D = rsc * Af + abar * rbr;
    nvd = fmaxf(D * eC * d_inv, 0.0f);

    int tn = (tt+1 < HT)? tt+1 : HT-1;
    mn = xls[tn];
    float eN = bf2f((unsigned)emTu[(size_t)mn*HN + j]);

    // [e] wave-local finalize (DPP), write plane wb
    float Mw = fmaxf(wmax_nn(nvd), 1e-30f);
    float sig = Mw * (1.0f/15.0f);
    int aq = __float2int_rn(nvd * (15.0f * rcpf(Mw)));
    float Sw = wsum_nn(nvd);
#if ENC_BIASED
    float AqSw = wsum_nn((float)aq);
#endif
    int aqn = xor1_i(aq);
    if((j&1)==0){
#if ENC_BIASED
      aplB[256*wb + (j>>1)] = (unsigned char)(((aq-8)&0xF) | (((aqn-8)&0xF)<<4));
#else
      aplB[256*wb + (j>>1)] = (unsigned char)((aq&0xF) | ((aqn&0xF)<<4));
#endif
    }
    if(L==0){
      sigS[8*wb+w] = sig; sumS[8*wb+w] = Sw;
#if ENC_BIASED
      aqS[8*wb+w] = AqSw;
#endif
    }
    eC = eN;
  }

  __syncthreads();
  {
    const int fb = (Tb & 1);
    float4 g0 = ((float4*)(sumS + 8*fb))[0], g1 = ((float4*)(sumS + 8*fb))[1];
    float Sf = ((g0.x+g0.y)+(g0.z+g0.w))+((g1.x+g1.y)+(g1.z+g1.w));
    if(t==0) out[b] = c_acc + __logf(Sf);
  }
}

extern "C" void kernel_launch(void* const* d_in, const int* in_sizes, int n_in,
                              void* d_out, int out_size, void* d_ws, size_t ws_size,
                              hipStream_t stream){
  const int*   x   = (const int*)d_in[0];
  const int*   T   = (const int*)d_in[1];
  const float* em  = (const float*)d_in[2];
  const float* tr  = (const float*)d_in[3];
  const float* pri = (const float*)d_in[4];
  float* out = (float*)d_out;

  char* ws = (char*)d_ws;
  float* em_lse = (float*)ws;                                   // 2 KiB
  float* P      = (float*)(ws + 2048);                          // 2 KiB
  float* pric   = (float*)(ws + 4096);                          // 16 B
  float* cmax   = (float*)(ws + 8192);                          // 2 KiB
  float* csum   = (float*)(ws + 10240);                         // 2 KiB
  float* rscale = (float*)(ws + 12288);                         // 2 KiB
  float* rbar   = (float*)(ws + 14336);                         // 2 KiB
  unsigned short* tsumq = (unsigned short*)(ws + 16384);        // 8 KiB
  unsigned short* emT = (unsigned short*)(ws + 24576);          // 4 MiB
  unsigned char*  TQ4 = (unsigned char*)(ws + 24576 + (size_t)HM*HN*2);  // 128 KiB

  k_em_lse<<<HN, 512, 0, stream>>>(em, em_lse);
  k_trcol <<<HN, 512, 0, stream>>>(tr, cmax, csum, pri, P, pric);
  k_trrow <<<HN, 512, 0, stream>>>(tr, cmax, csum, TQ4, rscale, rbar, tsumq);
  k_em_tab<<<dim3(HM/64, HN/64), 256, 0, stream>>>(em, em_lse, emT);

  const int lds_bytes = 131072 + 15104;   // 146176 B (<160 KiB/CU)
  (void)hipFuncSetAttribute((const void*)k_fwd, hipFuncAttributeMaxDynamicSharedMemorySize, lds_bytes);
  k_fwd<<<HB, 512, lds_bytes, stream>>>(x, T, emT, P, pric, rscale, rbar, tsumq,
                                        (const uint4*)TQ4, out);
}

// Round 11
// 485.632 us; speedup vs baseline: 1.2010x; 1.2010x over previous
//
#include <hip/hip_runtime.h>
#include <math.h>

#define HN 512   // hidden states
#define HM 4096  // emission symbols
#define HB 64    // batch
#define HT 512   // max seq len

// ---- 4-bit dot path (encoding must match between prep + fwd) ----
#if __has_builtin(__builtin_amdgcn_udot8)
  #define ENC_BIASED 0
  __device__ __forceinline__ int dot8q(unsigned int a, unsigned int b, int c){
    return (int)__builtin_amdgcn_udot8(a, b, (unsigned int)c, false);
  }
#elif __has_builtin(__builtin_amdgcn_sdot8)
  #define ENC_BIASED 1
  __device__ __forceinline__ int dot8q(unsigned int a, unsigned int b, int c){
    return __builtin_amdgcn_sdot8((int)a, (int)b, c, false);
  }
#else
  #define ENC_BIASED 0
  __device__ __forceinline__ int dot4u8f(unsigned int a, unsigned int b, int c){
#if __has_builtin(__builtin_amdgcn_sdot4)
    return __builtin_amdgcn_sdot4((int)a, (int)b, c, false);   // vals<=15, sign-safe
#else
    c += (int)(a & 0xffu)       * (int)(b & 0xffu);
    c += (int)((a>>8) & 0xffu)  * (int)((b>>8) & 0xffu);
    c += (int)((a>>16) & 0xffu) * (int)((b>>16) & 0xffu);
    c += (int)(a>>24)           * (int)(b>>24);
    return c;
#endif
  }
  __device__ __forceinline__ int dot8q(unsigned int a, unsigned int b, int c){
    unsigned int al = a & 0x0F0F0F0Fu, ah = (a>>4) & 0x0F0F0F0Fu;
    unsigned int bl = b & 0x0F0F0F0Fu, bh = (b>>4) & 0x0F0F0F0Fu;
    c = dot4u8f(al, bl, c);
    return dot4u8f(ah, bh, c);
  }
#endif

__device__ __forceinline__ float rcpf(float x){
#if __has_builtin(__builtin_amdgcn_rcpf)
  return __builtin_amdgcn_rcpf(x);
#else
  return 1.0f / x;
#endif
}

__device__ __forceinline__ float wsum(float v){
  #pragma unroll
  for(int o=32;o>0;o>>=1) v += __shfl_xor(v,o,64);
  return v;
}
__device__ __forceinline__ float wmax(float v){
  #pragma unroll
  for(int o=32;o>0;o>>=1) v = fmaxf(v,__shfl_xor(v,o,64));
  return v;
}

// ---- DPP wave64 reductions (VALU-latency, not DS-pipe) ----
#if __has_builtin(__builtin_amdgcn_update_dpp) && __has_builtin(__builtin_amdgcn_readlane)
#define HAVE_DPP 1
#define DPPF(v, ctrl, rmask) \
  __int_as_float(__builtin_amdgcn_update_dpp(0, __float_as_int(v), (ctrl), (rmask), 0xf, true))
__device__ __forceinline__ float wsum_nn(float v){   // sum of nonneg, result uniform
  v += DPPF(v, 0x111, 0xf);   // row_shr:1
  v += DPPF(v, 0x112, 0xf);   // row_shr:2
  v += DPPF(v, 0x114, 0xf);   // row_shr:4
  v += DPPF(v, 0x118, 0xf);   // row_shr:8
  v += DPPF(v, 0x142, 0xa);   // row_bcast:15 -> rows 1,3
  v += DPPF(v, 0x143, 0xc);   // row_bcast:31 -> rows 2,3
  return __int_as_float(__builtin_amdgcn_readlane(__float_as_int(v), 63));
}
__device__ __forceinline__ float wmax_nn(float v){   // max of nonneg, result uniform
  v = fmaxf(v, DPPF(v, 0x111, 0xf));
  v = fmaxf(v, DPPF(v, 0x112, 0xf));
  v = fmaxf(v, DPPF(v, 0x114, 0xf));
  v = fmaxf(v, DPPF(v, 0x118, 0xf));
  v = fmaxf(v, DPPF(v, 0x142, 0xa));
  v = fmaxf(v, DPPF(v, 0x143, 0xc));
  return __int_as_float(__builtin_amdgcn_readlane(__float_as_int(v), 63));
}
__device__ __forceinline__ int xor1_i(int v){        // lane^1 exchange, quad_perm [1,0,3,2]
  return __builtin_amdgcn_update_dpp(0, v, 0x0B1, 0xf, 0xf, true);
}
#else
#define HAVE_DPP 0
__device__ __forceinline__ float wsum_nn(float v){ return wsum(v); }
__device__ __forceinline__ float wmax_nn(float v){ return wmax(v); }
__device__ __forceinline__ int xor1_i(int v){ return __shfl_xor(v, 1, 64); }
#endif

__device__ __forceinline__ float blockSum512(float v, float* red, float* bc){
  v = wsum(v);
  if((threadIdx.x & 63)==0) red[threadIdx.x>>6] = v;
  __syncthreads();
  if(threadIdx.x < 64){
    float s = (threadIdx.x<8)? red[threadIdx.x] : 0.0f;
    #pragma unroll
    for(int o=4;o>0;o>>=1) s += __shfl_xor(s,o,64);
    if(threadIdx.x==0) *bc = s;
  }
  __syncthreads();
  return *bc;
}
__device__ __forceinline__ float blockMax512(float v, float* red, float* bc){
  v = wmax(v);
  if((threadIdx.x & 63)==0) red[threadIdx.x>>6] = v;
  __syncthreads();
  if(threadIdx.x < 64){
    float s = (threadIdx.x<8)? red[threadIdx.x] : -INFINITY;
    #pragma unroll
    for(int o=4;o>0;o>>=1) s = fmaxf(s, __shfl_xor(s,o,64));
    if(threadIdx.x==0) *bc = s;
  }
  __syncthreads();
  return *bc;
}

__device__ __forceinline__ unsigned short f2bf(float f){
  unsigned int u = __float_as_uint(f);
  unsigned int r = (u + 0x7fffu + ((u>>16)&1u)) >> 16;  // RNE
  return (unsigned short)r;
}
__device__ __forceinline__ float bf2f(unsigned int w){ return __uint_as_float(w<<16); }

// ---------------- prep kernels (fused: 2 launches instead of 4) ----------------
// ROUND 11: R9's k_pri fusion proved ~12us/launch (total moved 543->492.7 with
// k_fwd constant). Remaining independent work fused the same way:
//   launch A: blocks [0,512) = em_lse rows ; [512,1024) = trcol cols (+prior)
//   launch B: blocks [0,512) = trrow rows  ; [512,1024) = em_tab 64x64 tiles
// deps respected across the A->B boundary (trrow needs trcol, em_tab needs
// em_lse). k_fwd is VERBATIM R9 (best measured 420us).

__global__ __launch_bounds__(512) void k_prepA(const float* __restrict__ em, float* __restrict__ em_lse,
                                               const float* __restrict__ tr,
                                               float* __restrict__ cmax, float* __restrict__ csum,
                                               const float* __restrict__ pri,
                                               float* __restrict__ P, float* __restrict__ pric){
  __shared__ float red[8]; __shared__ float bc;
  if(blockIdx.x < 512){
    int r = blockIdx.x;
    const float* row = em + (size_t)r*HM;
    float mx = -INFINITY;
    for(int i=threadIdx.x;i<HM;i+=512) mx = fmaxf(mx, row[i]);
    mx = blockMax512(mx, red, &bc);
    float s = 0.f;
    for(int i=threadIdx.x;i<HM;i+=512) s += expf(row[i]-mx);
    s = blockSum512(s, red, &bc);
    if(threadIdx.x==0) em_lse[r] = mx + logf(s);
  } else {
    int k = blockIdx.x - 512, j = threadIdx.x;
    float v = tr[(size_t)j*HN + k];
    float mx = blockMax512(v, red, &bc);
    float s  = blockSum512(expf(v-mx), red, &bc);
    if(j==0){ cmax[k] = mx; csum[k] = s; }
    if(k == 0){
      float pv = pri[j];
      float pmx = blockMax512(pv, red, &bc);
      float pw = expf(pv-pmx);
      float ps = blockSum512(pw, red, &bc);
      P[j] = pw;
      if(j==0) *pric = -logf(ps);
    }
  }
}

// trrow: Tr[j,k] -> u4 q = round(Tr*15/rowmax). Byte at j*256 + (k>>5)*16 +
// ((k&31)>>1): lo = even k, hi = k+1 (matches alpha packing).
// em_tab: emT[m][j] = bf16(exp(log_em[j][m])), LDS-tiled transpose (512 thr).
__global__ __launch_bounds__(512) void k_prepB(const float* __restrict__ tr,
                                               const float* __restrict__ cmax, const float* __restrict__ csum,
                                               unsigned char* __restrict__ TQ4,
                                               float* __restrict__ rscale, float* __restrict__ rbar,
                                               unsigned short* __restrict__ tsumq,
                                               const float* __restrict__ em, const float* __restrict__ em_lse,
                                               unsigned short* __restrict__ emT){
  __shared__ float red[8]; __shared__ float bc;
  __shared__ unsigned short tile[64][66];
  __shared__ float lsl[64];
  if(blockIdx.x < 512){
    int j = blockIdx.x, k = threadIdx.x;
    float v = expf(tr[(size_t)j*HN + k] - cmax[k]) / csum[k];
    float rm = blockMax512(v, red, &bc);
    int q = __float2int_rn(v * (15.0f/rm));          // 0..15
    float rs = blockSum512(v, red, &bc);             // true row sum
    float qs = blockSum512((float)q, red, &bc);      // total q sum
    float wq = wsum((float)q);                       // per-wave(64k) q sum
    int qn = __shfl_down(q, 1, 64);
    if((k & 1)==0){
#if ENC_BIASED
      unsigned char by = (unsigned char)(((q-8)&0xF) | (((qn-8)&0xF)<<4));
#else
      unsigned char by = (unsigned char)((q&0xF) | ((qn&0xF)<<4));
#endif
      TQ4[(size_t)j*256 + ((k>>5)<<4) + ((k&31)>>1)] = by;
    }
    if((k&63)==0) tsumq[j*8 + (k>>6)] = (unsigned short)(int)wq;
    if(k==0){
      rscale[j] = rm * (1.0f/15.0f);
      rbar[j]   = rs - (rm * (1.0f/15.0f)) * qs;
    }
  } else {
    int q = blockIdx.x - 512;                    // 512 tiles = 64 m-tiles x 8 j-tiles
    int m0 = (q & 63)*64, j0 = (q >> 6)*64;
    int tx = threadIdx.x & 63, ty = threadIdx.x >> 6;   // ty in [0,8)
    if(threadIdx.x < 64) lsl[threadIdx.x] = em_lse[j0 + threadIdx.x];
    __syncthreads();
    #pragma unroll
    for(int r=0;r<8;r++){
      int jl = ty*8 + r;
      float v = em[(size_t)(j0+jl)*HM + m0 + tx];
      tile[jl][tx] = f2bf(expf(v - lsl[jl]));
    }
    __syncthreads();
    #pragma unroll
    for(int r=0;r<8;r++){
      int ml = ty*8 + r;
      emT[(size_t)(m0+ml)*HN + j0 + tx] = tile[tx][ml];
    }
  }
}

// ---------------- forward recurrence (VERBATIM R9 best: 420us, VGPR 48) ----
// 64 blocks (1/batch), 512 threads = 8 waves. ONE barrier/step, ping-pong
// alpha/stats planes, stale-S normalizer, wave-local DPP finalize, Tr via
// scratch stream (the measured L1 floor: 128 KB/step at ~64 B/cyc = 1960
// cyc/step). R3-R10 falsified every relocation of this stream (LDS, AGPR,
// named regs, pipe-splits with/without waves_per_eu); this is the floor of
// this structure.
__global__ __launch_bounds__(512, 1)
void k_fwd(const int* __restrict__ x, const int* __restrict__ Tl,
           const unsigned short* __restrict__ emTu,
           const float* __restrict__ P, const float* __restrict__ pric,
           const float* __restrict__ rscaleG, const float* __restrict__ rbarG,
           const unsigned short* __restrict__ tsumqG,
           const uint4* __restrict__ TQd4,
           float* __restrict__ out){
  extern __shared__ char smem[];
  uint4*         apl4  = (uint4*)smem;                         // [2][16] uint4 = 512 B
  unsigned char* aplB  = (unsigned char*)smem;
  float*         sigS  = (float*)(smem + 512);                 // [2][8]
  float*         sumS  = (float*)(smem + 576);                 // [2][8]
  float*         aqS   = (float*)(smem + 640);                 // [2][8]
  float*         rawS  = (float*)(smem + 704);                 // [8]
  int*           xls   = (int*)(smem + 768);                   // 2048
  float*         rscL  = (float*)(smem + 2816);                // 2048
  float*         rbarL = (float*)(smem + 4864);                // 2048
  unsigned short* tsumL= (unsigned short*)(smem + 6912);       // 8192
  // total 15104 B

  const int t = threadIdx.x, b = blockIdx.x, w = t>>6, L = t&63;
  const int j = t;

  const uint4* trp = TQd4 + (size_t)j*16;
  unsigned int trq[48];
  #pragma unroll
  for(int q=0;q<12;q++) ((uint4*)trq)[q] = trp[q];
  #pragma unroll
  for(int r=0;r<48;r++) asm volatile("" : "+v"(trq[r]));
  uint4 c12 = trp[12], c13 = trp[13], c14 = trp[14], c15 = trp[15];

  xls[t]   = x[b*HT + t];
  rscL[t]  = rscaleG[t];
  rbarL[t] = rbarG[t];
  for(int d=t; d<2048; d+=512) ((unsigned int*)tsumL)[d] = ((const unsigned int*)tsumqG)[d];
  int Tb = Tl[b];
  __syncthreads();

  // ---- init (t = 0) ----
  int m = xls[0];
  float e0 = bf2f((unsigned)emTu[(size_t)m*HN + j]);
  float nvr = e0 * P[j];
  {
    float s = wsum_nn(nvr);
    if(L==0) rawS[w] = s;
  }
  __syncthreads();
  float4 q0 = ((float4*)rawS)[0], q1 = ((float4*)rawS)[1];
  float S0 = ((q0.x+q0.y)+(q0.z+q0.w))+((q1.x+q1.y)+(q1.z+q1.w));
  float c_acc = pric[0] + __logf(S0);
  float nvd = nvr * rcpf(S0);
  {
    float Mw = fmaxf(wmax_nn(nvd), 1e-30f);
    float sig = Mw * (1.0f/15.0f);
    int aq = __float2int_rn(nvd * (15.0f * rcpf(Mw)));
    float Sw = wsum_nn(nvd);
#if ENC_BIASED
    float AqSw = wsum_nn((float)aq);
#endif
    int aqn = xor1_i(aq);
    if((j&1)==0){
#if ENC_BIASED
      aplB[256 + (j>>1)] = (unsigned char)(((aq-8)&0xF) | (((aqn-8)&0xF)<<4));
#else
      aplB[256 + (j>>1)] = (unsigned char)((aq&0xF) | ((aqn&0xF)<<4));
#endif
    }
    if(L==0){
      sigS[8+w] = sig; sumS[8+w] = Sw;
#if ENC_BIASED
      aqS[8+w] = AqSw;
#endif
    }
  }
  int mn = xls[(Tb>1)?1:0];
  float eC = bf2f((unsigned)emTu[(size_t)mn*HN + j]);
  const float rsc = rscL[j], rbr = rbarL[j];

  for(int tt=1; tt<Tb; tt++){
    __syncthreads();                      // the ONE barrier per step
    const int rb = (tt & 1), wb = rb ^ 1;

    // [a] full-row dot: 16 alpha chunks (wave-uniform b128 broadcast);
    //     Tr chunks 0..11 from scratch (vmem pipe), 12..15 from registers
    int acc[8];
    #pragma unroll
    for(int i=0;i<8;i++) acc[i] = 0;
    const uint4* aplR = apl4 + 16*rb;
    #pragma unroll
    for(int c=0;c<12;c++){
      uint4 A = aplR[c];
      int wi = c>>1;
      acc[wi] = dot8q(trq[4*c+0], A.x, acc[wi]);
      acc[wi] = dot8q(trq[4*c+1], A.y, acc[wi]);
      acc[wi] = dot8q(trq[4*c+2], A.z, acc[wi]);
      acc[wi] = dot8q(trq[4*c+3], A.w, acc[wi]);
    }
    {
      uint4 A = aplR[12];
      acc[6] = dot8q(c12.x, A.x, acc[6]);
      acc[6] = dot8q(c12.y, A.y, acc[6]);
      acc[6] = dot8q(c12.z, A.z, acc[6]);
      acc[6] = dot8q(c12.w, A.w, acc[6]);
      A = aplR[13];
      acc[6] = dot8q(c13.x, A.x, acc[6]);
      acc[6] = dot8q(c13.y, A.y, acc[6]);
      acc[6] = dot8q(c13.z, A.z, acc[6]);
      acc[6] = dot8q(c13.w, A.w, acc[6]);
      A = aplR[14];
      acc[7] = dot8q(c14.x, A.x, acc[7]);
      acc[7] = dot8q(c14.y, A.y, acc[7]);
      acc[7] = dot8q(c14.z, A.z, acc[7]);
      acc[7] = dot8q(c14.w, A.w, acc[7]);
      A = aplR[15];
      acc[7] = dot8q(c15.x, A.x, acc[7]);
      acc[7] = dot8q(c15.y, A.y, acc[7]);
      acc[7] = dot8q(c15.z, A.z, acc[7]);
      acc[7] = dot8q(c15.w, A.w, acc[7]);
    }

    // [b] previous-step stats (uniform reads)
    float4 g0 = ((float4*)(sumS + 8*rb))[0], g1 = ((float4*)(sumS + 8*rb))[1];
    float Sp = ((g0.x+g0.y)+(g0.z+g0.w))+((g1.x+g1.y)+(g1.z+g1.w));
    if(tt > 1) c_acc += __logf(Sp);
    float d_inv = rcpf(Sp);
    float abar  = Sp * (1.0f/512.0f);
    float4 s0 = ((float4*)(sigS + 8*rb))[0], s1 = ((float4*)(sigS + 8*rb))[1];
    float sg[8] = {s0.x,s0.y,s0.z,s0.w,s1.x,s1.y,s1.z,s1.w};

    // [c] combine with per-slice alpha scales (+ sdot bias correction)
    float Af = 0.f;
#if ENC_BIASED
    {
      float4 a0 = ((float4*)(aqS + 8*rb))[0], a1 = ((float4*)(aqS + 8*rb))[1];
      float av[8] = {a0.x,a0.y,a0.z,a0.w,a1.x,a1.y,a1.z,a1.w};
      uint4 tq = ((const uint4*)tsumL)[j];
      int ts[8] = {(int)(tq.x&0xffff),(int)(tq.x>>16),(int)(tq.y&0xffff),(int)(tq.y>>16),
                   (int)(tq.z&0xffff),(int)(tq.z>>16),(int)(tq.w&0xffff),(int)(tq.w>>16)};
      #pragma unroll
      for(int i=0;i<8;i++)
        Af += sg[i] * (float)(acc[i] + 8*(ts[i] + (int)av[i]) - 4096);
    }
#else
    #pragma unroll
    for(int i=0;i<8;i++) Af += sg[i] * (float)acc[i];
#endif
    float D = rsc * Af + abar * rbr;
    nvd = fmaxf(D * eC * d_inv, 0.0f);

    // prefetch next emission
    int tn = (tt+1 < HT)? tt+1 : HT-1;
    mn = xls[tn];
    float eN = bf2f((unsigned)emTu[(size_t)mn*HN + j]);

    // [e] wave-local finalize: quantize vs wave max (DPP reduce), write plane wb
    float Mw = fmaxf(wmax_nn(nvd), 1e-30f);
    float sig = Mw * (1.0f/15.0f);
    int aq = __float2int_rn(nvd * (15.0f * rcpf(Mw)));
    float Sw = wsum_nn(nvd);
#if ENC_BIASED
    float AqSw = wsum_nn((float)aq);
#endif
    int aqn = xor1_i(aq);
    if((j&1)==0){
#if ENC_BIASED
      aplB[256*wb + (j>>1)] = (unsigned char)(((aq-8)&0xF) | (((aqn-8)&0xF)<<4));
#else
      aplB[256*wb + (j>>1)] = (unsigned char)((aq&0xF) | ((aqn&0xF)<<4));
#endif
    }
    if(L==0){
      sigS[8*wb+w] = sig; sumS[8*wb+w] = Sw;
#if ENC_BIASED
      aqS[8*wb+w] = AqSw;
#endif
    }
    eC = eN;
  }

  // ---- flush last step's S ----
  __syncthreads();
  {
    const int fb = (Tb & 1);
    float4 g0 = ((float4*)(sumS + 8*fb))[0], g1 = ((float4*)(sumS + 8*fb))[1];
    float Sf = ((g0.x+g0.y)+(g0.z+g0.w))+((g1.x+g1.y)+(g1.z+g1.w));
    if(t==0) out[b] = c_acc + __logf(Sf);
  }
}

extern "C" void kernel_launch(void* const* d_in, const int* in_sizes, int n_in,
                              void* d_out, int out_size, void* d_ws, size_t ws_size,
                              hipStream_t stream){
  const int*   x   = (const int*)d_in[0];
  const int*   T   = (const int*)d_in[1];
  const float* em  = (const float*)d_in[2];
  const float* tr  = (const float*)d_in[3];
  const float* pri = (const float*)d_in[4];
  float* out = (float*)d_out;

  char* ws = (char*)d_ws;
  float* em_lse = (float*)ws;                                   // 2 KiB
  float* P      = (float*)(ws + 2048);                          // 2 KiB
  float* pric   = (float*)(ws + 4096);                          // 16 B
  float* cmax   = (float*)(ws + 8192);                          // 2 KiB
  float* csum   = (float*)(ws + 10240);                         // 2 KiB
  float* rscale = (float*)(ws + 12288);                         // 2 KiB
  float* rbar   = (float*)(ws + 14336);                         // 2 KiB
  unsigned short* tsumq = (unsigned short*)(ws + 16384);        // 8 KiB
  unsigned short* emT = (unsigned short*)(ws + 24576);          // 4 MiB
  unsigned char*  TQ4 = (unsigned char*)(ws + 24576 + (size_t)HM*HN*2);  // 128 KiB

  k_prepA<<<1024, 512, 0, stream>>>(em, em_lse, tr, cmax, csum, pri, P, pric);
  k_prepB<<<1024, 512, 0, stream>>>(tr, cmax, csum, TQ4, rscale, rbar, tsumq,
                                    em, em_lse, emT);

  const int lds_bytes = 15104;
  (void)hipFuncSetAttribute((const void*)k_fwd, hipFuncAttributeMaxDynamicSharedMemorySize, lds_bytes);
  k_fwd<<<HB, 512, lds_bytes, stream>>>(x, T, emT, P, pric, rscale, rbar, tsumq,
                                        (const uint4*)TQ4, out);
}